// Round 7
// baseline (97.275 us; speedup 1.0000x reference)
//
#include <hip/hip_runtime.h>

// Hankel anti-diagonal segmented mean.
// Input:  delay_embedding [B=64, T=1024, E=2048] fp32
// Output: [B, E-1=2047] fp32; out[b,k] = mean over i of A[b, i, 1024+k-i],
//         i in [max(0, k-1023), 1023].
//
// R7: ALIGNED ROW STREAMS. Row i contributes exactly j in [1024-i, 2048)
// (k = i+j-1024 in [0, 1023+i]). Waves stream whole rows with aligned
// dwordx4 (rows are 8KB-aligned; window start rounded down to 128B) -> zero
// cache-line splits, fetch ~= 406 MB (vs ~452 MB for the unaligned diagonal
// walk). Each quad scatters into a PER-WAVE LDS accumulator at idx k+32
// (consecutive j -> consecutive k -> conflict-free b128 rmw). Validity k>=0
// via branchless select; k<0 pads add 0.0 into scratch slots [1,32).
//
// Balance by construction: width(i)+width(1023-i) = 3071 = const. Block p
// owns low rows [32p,32p+32) + high rows [992-32p,1024-32p); wave w takes
// low 8w..+8 and high 8(3-w)..+8 -> identical work per wave and per block.
// 16 p x 64 b = 1024 blocks = exactly 4/CU (LDS 33KB -> 4 fit), all resident.
//
// Epilogue: combine the 4 waves' accumulators, scale by 1/cnt(k), and
// unsafeAtomicAdd (HW global_atomic_add_f32) into memset-zeroed out;
// k-order staggered by p to spread slot contention (16 blocks per out slot).

#define T_LEN 1024
#define E_LEN 2048
#define K_OUT (E_LEN - 1)   // 2047
#define B_SZ  64
#define NP    16            // row-pair chunk index
#define NBLK  (NP * B_SZ)   // 1024 blocks
#define LSTR  2080          // per-wave accumulator floats: idx = k+32, k in [-31,2047]

__global__ void __launch_bounds__(256)
diag_accum(const float* __restrict__ in, float* __restrict__ out) {
    __shared__ float lacc[4][LSTR];   // 33.3 KB

    const int b    = blockIdx.x & (B_SZ - 1);
    const int p    = blockIdx.x >> 6;        // 0..15
    const int w    = threadIdx.x >> 6;       // wave 0..3
    const int lane = threadIdx.x & 63;

    // Zero own wave's accumulator region (wave-private: no barrier needed).
    float* acc = lacc[w];
    for (int t = lane; t < LSTR; t += 64) acc[t] = 0.0f;

    const float* inb = in + (size_t)b * T_LEN * E_LEN;

    // 16 rows/wave: 8 low (i = 32p+8w+r), 8 high (i = 992-32p+8*(3-w)+r).
    for (int r = 0; r < 16; ++r) {
        const int i = (r < 8) ? (32 * p + 8 * w + r)
                              : (992 - 32 * p + 8 * (3 - w) + (r - 8));
        const int jmin = T_LEN - i;           // k>=0  <=>  j >= jmin
        const int jb   = jmin & ~31;          // 128B-aligned window start
        const int kofs = i - T_LEN + 32;      // LDS idx = j + kofs (>= 1)
        const float* rowp = inb + (size_t)i * E_LEN;

        #pragma unroll 2
        for (int j4 = jb + 4 * lane; j4 < E_LEN; j4 += 256) {
            float v[4];
            __builtin_memcpy(v, rowp + j4, 16);   // aligned global dwordx4
            float* a = &acc[j4 + kofs];
            // Conflict-free b128 rmw; head pads (k<0) add 0 into scratch.
            const float a0 = a[0], a1 = a[1], a2 = a[2], a3 = a[3];
            a[0] = a0 + ((j4 + 0 >= jmin) ? v[0] : 0.0f);
            a[1] = a1 + ((j4 + 1 >= jmin) ? v[1] : 0.0f);
            a[2] = a2 + ((j4 + 2 >= jmin) ? v[2] : 0.0f);
            a[3] = a3 + ((j4 + 3 >= jmin) ? v[3] : 0.0f);
        }
    }

    __syncthreads();

    // Combine 4 waves, scale by 1/cnt(k), HW f32 atomic into out.
    // Stagger k-order across blocks (by p) to spread atomic contention.
    #pragma unroll
    for (int m = 0; m < 8; ++m) {
        const int k = (int)threadIdx.x + 256 * (m ^ (p & 7));
        if (k < K_OUT) {
            const float v = lacc[0][k + 32] + lacc[1][k + 32]
                          + lacc[2][k + 32] + lacc[3][k + 32];
            const int cnt = T_LEN - max(0, k - (T_LEN - 1));
            unsafeAtomicAdd(&out[(size_t)b * K_OUT + k], v * (1.0f / (float)cnt));
        }
    }
}

extern "C" void kernel_launch(void* const* d_in, const int* in_sizes, int n_in,
                              void* d_out, int out_size, void* d_ws, size_t ws_size,
                              hipStream_t stream) {
    const float* in = (const float*)d_in[0];
    float* out = (float*)d_out;

    // Zero the accumulator (d_out is poisoned once, never re-poisoned).
    hipMemsetAsync(out, 0, sizeof(float) * B_SZ * K_OUT, stream);

    diag_accum<<<NBLK, 256, 0, stream>>>(in, out);
}

// Round 8
// 86.785 us; speedup vs baseline: 1.1209x; 1.1209x over previous
//
#include <hip/hip_runtime.h>

// Hankel anti-diagonal segmented mean.
// Input:  delay_embedding [B=64, T=1024, E=2048] fp32
// Output: [B, E-1=2047] fp32; out[b,k] = mean over i of A[b, i, 1024+k-i],
//         i in [max(0, k-1023), 1023].
//
// R5 structure (empirical Pareto-best: 86.0 us) + unroll 16 for deeper MLP.
// For fixed row i, diagonal elements for consecutive k are contiguous:
// A[b,i,1024+k-i] = in[b*T*E + i*(E-1) + (T+k)] -> coalesced float4 reads,
// every input element read exactly once (402 MB -> HBM-bound).
//
// Decomposition: unit = (b, 512-k group G, 64-row chunk rc, k-half p).
// Block = 4 waves, same (b,G): wave w -> chunk rc = rcb+(w>>1), half p = w&1.
// Only valid (G,rc) pairs enumerated: G=0,1,2 full-ish (8 blocks each),
// G=3 rc>=8 (4) -> 28 blocks/batch, 1792 total: all co-resident (7/CU,
// 28 waves/CU), near-uniform weight. Waves write partials to private LDS
// (plain stores, no init); one barrier; combined values -> HW f32 atomics
// (unsafeAtomicAdd = global_atomic_add_f32) into memset-zeroed d_out.

#define T_LEN 1024
#define E_LEN 2048
#define K_OUT (E_LEN - 1)   // 2047
#define B_SZ  64
#define NBLK  (28 * B_SZ)   // 1792

__global__ void __launch_bounds__(256)
diag_accum(const float* __restrict__ in, float* __restrict__ out) {
    __shared__ float lacc[1024];   // 4 KB: [wave][256 k-slots]

    const int b  = blockIdx.x & (B_SZ - 1);
    const int u2 = blockIdx.x >> 6;          // 0..27

    int G, rcb;
    if (u2 < 8)       { G = 0; rcb = u2 * 2;            }
    else if (u2 < 16) { G = 1; rcb = (u2 - 8) * 2;      }
    else if (u2 < 24) { G = 2; rcb = (u2 - 16) * 2;     }
    else              { G = 3; rcb = 8 + (u2 - 24) * 2; }

    const int w    = threadIdx.x >> 6;       // wave 0..3
    const int lane = threadIdx.x & 63;
    const int rc   = rcb + (w >> 1);         // chunk for this wave
    const int p    = w & 1;                  // k-half

    const int k0 = G * 512 + p * 256 + (lane << 2);   // 4 consecutive k's
    const int r0 = rc * 64;
    const int r1 = r0 + 64;

    int il0       = max(r0, k0     - (T_LEN - 1));
    const int il3 = max(r0, k0 + 3 - (T_LEN - 1));

    float sx = 0.f, sy = 0.f, sz = 0.f, sw = 0.f;
    if (il0 < r1) {
        const float* pp = in + (size_t)b * T_LEN * E_LEN
                             + (size_t)il0 * (E_LEN - 1)
                             + (size_t)(T_LEN + k0);
        int i = il0;

        // Ragged diagonal head (<=3 iters; whole chunk only at the k0=2044
        // corner, which also keeps comp3 from reading past the buffer).
        const int head_end = min(il3, r1);
        for (; i < head_end; ++i) {
            sx += pp[0];
            if (i >= k0 + 1 - (T_LEN - 1)) sy += pp[1];
            if (i >= k0 + 2 - (T_LEN - 1)) sz += pp[2];
            pp += (E_LEN - 1);
        }

        // Main loop: all 4 components valid and in-bounds. Unroll 16 ->
        // 16 independent dwordx4 in flight per wave (deeper MLP than R5's 8).
        #pragma unroll 16
        for (; i < r1; ++i) {
            float v[4];
            __builtin_memcpy(v, pp, 16);   // unaligned-safe -> dwordx4
            sx += v[0]; sy += v[1]; sz += v[2]; sw += v[3];
            pp += (E_LEN - 1);
        }
    }

    // Private LDS region per wave (plain stores, no init: idle lanes wrote 0).
    float4* dst = (float4*)&lacc[w * 256 + (lane << 2)];
    *dst = make_float4(sx, sy, sz, sw);
    __syncthreads();

    // Combine wave pairs {0,2} and {1,3}, scale by 1/cnt(k), HW f32 atomic.
    #pragma unroll 2
    for (int t = threadIdx.x; t < 512; t += 256) {
        const int k = G * 512 + t;
        if (k < K_OUT) {
            const float v = lacc[t] + lacc[512 + t];
            const int cnt = T_LEN - max(0, k - (T_LEN - 1));
            unsafeAtomicAdd(&out[(size_t)b * K_OUT + k], v * (1.0f / (float)cnt));
        }
    }
}

extern "C" void kernel_launch(void* const* d_in, const int* in_sizes, int n_in,
                              void* d_out, int out_size, void* d_ws, size_t ws_size,
                              hipStream_t stream) {
    const float* in = (const float*)d_in[0];
    float* out = (float*)d_out;

    // Zero the accumulator (d_out is poisoned once, never re-poisoned).
    hipMemsetAsync(out, 0, sizeof(float) * B_SZ * K_OUT, stream);

    diag_accum<<<NBLK, 256, 0, stream>>>(in, out);
}